// Round 1
// baseline (502.232 us; speedup 1.0000x reference)
//
#include <hip/hip_runtime.h>

#define NN 50000
#define NE 800000

typedef _Float16 half8 __attribute__((ext_vector_type(8)));
typedef float f32x4 __attribute__((ext_vector_type(4)));

__device__ __forceinline__ float sigm(float x) { return 1.0f / (1.0f + __expf(-x)); }

// ---------- prep: W (f32 [k][n] 128x128) -> W^T (f16 [n][k]) in ws ----------
__global__ void prepw_kernel(const float* __restrict__ w0, const float* __restrict__ w1,
                             const float* __restrict__ w2, _Float16* __restrict__ wt) {
  const float* w = blockIdx.x == 0 ? w0 : (blockIdx.x == 1 ? w1 : w2);
  _Float16* o = wt + blockIdx.x * 16384;
  int t = threadIdx.x;
  for (int it = 0; it < 64; ++it) {
    int flat = it * 256 + t;        // coalesced read of W
    int k = flat >> 7, n = flat & 127;
    o[n * 128 + k] = (_Float16)w[flat];
  }
}

// ---------- degree histogram ----------
__global__ void hist_kernel(const int* __restrict__ eidx, unsigned* __restrict__ cnt) {
  int e = blockIdx.x * 256 + threadIdx.x;
  if (e < NE) atomicAdd(&cnt[eidx[2 * e]], 1u);
}

// ---------- node GEMM: nh = nf @ Wn + bn  (fp32 out) ----------
__global__ __launch_bounds__(512, 2) void node_kernel(
    const float* __restrict__ nf, const _Float16* __restrict__ wnT,
    const float* __restrict__ bnp, float* __restrict__ nh) {
  __shared__ __align__(16) char wl[32768];   // WnT f16 swizzled
  __shared__ __align__(16) char tl[65536];   // 256 rows x 128 f16 swizzled

  const int t = threadIdx.x;
  const int lane = t & 63;
  const int wave = t >> 6;          // 0..7
  const int wm = wave >> 2;         // 0..1 : 128-row group
  const int wn = wave & 3;          // 0..3 : 32-col group

  // stage W^T: 16384 halfs, 8 halfs/thread/iter, 4 iters
  for (int it = 0; it < 4; ++it) {
    int h8 = it * 512 + t;          // 0..2047
    int n = h8 >> 4, k8 = h8 & 15;
    half8 v = *(const half8*)(wnT + n * 128 + k8 * 8);
    *(half8*)(wl + ((n * 256 + k8 * 16) ^ ((n & 7) << 4))) = v;
  }

  const int tile = blockIdx.x;
  const int row0 = tile * 256;
  // stage node tile fp32 -> f16, swizzled
  for (int it = 0; it < 8; ++it) {
    int idx8 = it * 512 + t;        // 0..4095, 8 floats each
    int row = idx8 >> 4, col8 = idx8 & 15;
    int grow = row0 + row;
    half8 h;
    if (grow < NN) {
      const float4* s = (const float4*)(nf + (size_t)grow * 128 + col8 * 8);
      float4 a = s[0], b = s[1];
      h[0] = (_Float16)a.x; h[1] = (_Float16)a.y; h[2] = (_Float16)a.z; h[3] = (_Float16)a.w;
      h[4] = (_Float16)b.x; h[5] = (_Float16)b.y; h[6] = (_Float16)b.z; h[7] = (_Float16)b.w;
    } else {
#pragma unroll
      for (int j = 0; j < 8; ++j) h[j] = (_Float16)0.0f;
    }
    *(half8*)(tl + ((row * 256 + col8 * 16) ^ ((row & 7) << 4))) = h;
  }
  __syncthreads();

  const int c0 = wn * 32 + (lane & 15);
  const int arow = wm * 128 + (lane & 15);
  const int akb = (lane >> 4) * 16;

  f32x4 acc[8][2] = {};
#pragma unroll
  for (int ks = 0; ks < 4; ++ks) {
    int kb = ks * 64 + akb;
    half8 B0 = *(half8*)(wl + c0 * 256 + (kb ^ ((c0 & 7) << 4)));
    half8 B1 = *(half8*)(wl + (c0 + 16) * 256 + (kb ^ ((c0 & 7) << 4)));
#pragma unroll
    for (int mi = 0; mi < 8; ++mi) {
      int r = arow + mi * 16;
      half8 A = *(half8*)(tl + r * 256 + (kb ^ ((r & 7) << 4)));
      acc[mi][0] = __builtin_amdgcn_mfma_f32_16x16x32_f16(A, B0, acc[mi][0], 0, 0, 0);
      acc[mi][1] = __builtin_amdgcn_mfma_f32_16x16x32_f16(A, B1, acc[mi][1], 0, 0, 0);
    }
  }

  const float b0 = bnp[c0], b1 = bnp[c0 + 16];
#pragma unroll
  for (int mi = 0; mi < 8; ++mi) {
#pragma unroll
    for (int r = 0; r < 4; ++r) {
      int grow = row0 + wm * 128 + mi * 16 + (lane >> 4) * 4 + r;
      if (grow < NN) {
        nh[(size_t)grow * 128 + c0] = acc[mi][0][r] + b0;
        nh[(size_t)grow * 128 + c0 + 16] = acc[mi][1][r] + b1;
      }
    }
  }
}

// ---------- fused edge kernel: gate/filt GEMM + gather + scatter-add ----------
#define NTILES 3125   // 800000 / 256
__global__ __launch_bounds__(512, 2) void edge_kernel(
    const float* __restrict__ ef, const int* __restrict__ eidx,
    const _Float16* __restrict__ wgT, const _Float16* __restrict__ wfT,
    const float* __restrict__ bgp, const float* __restrict__ bfp,
    const float* __restrict__ nh, float* __restrict__ sums) {
  __shared__ __align__(16) char wl[65536];   // WgT [0,32768) | WfT [32768,65536), swizzled
  __shared__ __align__(16) char tl[65536];   // edge tile 256x128 f16, swizzled
  __shared__ int il[512];                    // edge indices (src,dst) x 256

  const int t = threadIdx.x;
  const int lane = t & 63;
  const int wave = t >> 6;
  const int wm = wave >> 2;   // 0..1: 128-edge group
  const int wn = wave & 3;    // 0..3: 32-col group (gate AND filt)

  // stage both W^T (once per block): 32768 halfs total
  for (int it = 0; it < 8; ++it) {
    int h8 = it * 512 + t;                      // 0..4095 (8-half chunks)
    const _Float16* src = (h8 < 2048) ? wgT : wfT;
    int loc = h8 & 2047;
    int n = loc >> 4, k8 = loc & 15;
    half8 v = *(const half8*)(src + n * 128 + k8 * 8);
    int off = ((h8 < 2048) ? 0 : 32768) + n * 256 + k8 * 16;
    *(half8*)(wl + (off ^ ((n & 7) << 4))) = v;
  }

  const int c0 = wn * 32 + (lane & 15);
  const float bg0 = bgp[c0], bg1 = bgp[c0 + 16];
  const float bf0 = bfp[c0], bf1 = bfp[c0 + 16];
  const int arow = wm * 128 + (lane & 15);
  const int akb = (lane >> 4) * 16;

  for (int tile = blockIdx.x; tile < NTILES; tile += gridDim.x) {
    __syncthreads();   // previous iteration's readers done before we overwrite tl/il

    il[t] = eidx[(size_t)tile * 512 + t];

    const float* src = ef + (size_t)tile * 32768;
    for (int it = 0; it < 8; ++it) {
      int f8 = it * 4096 + t * 8;
      const float4* s = (const float4*)(src + f8);
      float4 a = s[0], b = s[1];
      half8 h;
      h[0] = (_Float16)a.x; h[1] = (_Float16)a.y; h[2] = (_Float16)a.z; h[3] = (_Float16)a.w;
      h[4] = (_Float16)b.x; h[5] = (_Float16)b.y; h[6] = (_Float16)b.z; h[7] = (_Float16)b.w;
      int idx8 = f8 >> 3;
      int row = idx8 >> 4, col16 = (idx8 & 15) * 16;
      *(half8*)(tl + ((row * 256 + col16) ^ ((row & 7) << 4))) = h;
    }
    __syncthreads();

    // GEMM: 128 edges x {32 gate cols + 32 filt cols} per wave
    f32x4 acc[8][4] = {};   // [mi][g0,g1,f0,f1]
#pragma unroll
    for (int ks = 0; ks < 4; ++ks) {
      int kb = ks * 64 + akb;
      int bx = kb ^ ((c0 & 7) << 4);
      half8 Bg0 = *(half8*)(wl + c0 * 256 + bx);
      half8 Bg1 = *(half8*)(wl + (c0 + 16) * 256 + bx);
      half8 Bf0 = *(half8*)(wl + 32768 + c0 * 256 + bx);
      half8 Bf1 = *(half8*)(wl + 32768 + (c0 + 16) * 256 + bx);
#pragma unroll
      for (int mi = 0; mi < 8; ++mi) {
        int r = arow + mi * 16;
        half8 A = *(half8*)(tl + r * 256 + (kb ^ ((r & 7) << 4)));
        acc[mi][0] = __builtin_amdgcn_mfma_f32_16x16x32_f16(A, Bg0, acc[mi][0], 0, 0, 0);
        acc[mi][1] = __builtin_amdgcn_mfma_f32_16x16x32_f16(A, Bg1, acc[mi][1], 0, 0, 0);
        acc[mi][2] = __builtin_amdgcn_mfma_f32_16x16x32_f16(A, Bf0, acc[mi][2], 0, 0, 0);
        acc[mi][3] = __builtin_amdgcn_mfma_f32_16x16x32_f16(A, Bf1, acc[mi][3], 0, 0, 0);
      }
    }

    // epilogue: message = sigmoid(gate) * filt * nh[dst], atomicAdd into sums[src]
#pragma unroll
    for (int mi = 0; mi < 8; ++mi) {
#pragma unroll
      for (int r = 0; r < 4; ++r) {
        int el = wm * 128 + mi * 16 + (lane >> 4) * 4 + r;   // local edge id
        int srcn = il[el * 2];
        int dstn = il[el * 2 + 1];
        float g0 = sigm(acc[mi][0][r] + bg0);
        float g1 = sigm(acc[mi][1][r] + bg1);
        float f0 = acc[mi][2][r] + bf0;
        float f1 = acc[mi][3][r] + bf1;
        float m0 = g0 * f0 * nh[(size_t)dstn * 128 + c0];
        float m1 = g1 * f1 * nh[(size_t)dstn * 128 + c0 + 16];
        atomicAdd(&sums[(size_t)srcn * 128 + c0], m0);
        atomicAdd(&sums[(size_t)srcn * 128 + c0 + 16], m1);
      }
    }
  }
}

// ---------- finalize: out = relu(bn(nh + agg)) ----------
__global__ void finalize_kernel(const float* __restrict__ nh, const float* __restrict__ sums,
                                const unsigned* __restrict__ cnt,
                                const float* __restrict__ gamma, const float* __restrict__ beta,
                                const float* __restrict__ mean, const float* __restrict__ var,
                                float* __restrict__ out) {
  int i = blockIdx.x * 256 + threadIdx.x;     // float4 index
  if (i >= NN * 32) return;
  int row = i >> 5;
  int c = (i & 31) * 4;
  float cf = (float)cnt[row];
  float inv = cf > 0.0f ? 1.0f / cf : 0.0f;
  float4 s = ((const float4*)sums)[i];
  float4 h = ((const float4*)nh)[i];
  float4 o;
#define BN1(comp, j)                                                            \
  {                                                                             \
    float sc = rsqrtf(var[c + j] + 0.001f) * gamma[c + j];                      \
    float v = (h.comp + s.comp * inv - mean[c + j]) * sc + beta[c + j];         \
    o.comp = fmaxf(v, 0.0f);                                                    \
  }
  BN1(x, 0) BN1(y, 1) BN1(z, 2) BN1(w, 3)
#undef BN1
  ((float4*)out)[i] = o;
}

extern "C" void kernel_launch(void* const* d_in, const int* in_sizes, int n_in,
                              void* d_out, int out_size, void* d_ws, size_t ws_size,
                              hipStream_t stream) {
  const float* nf    = (const float*)d_in[0];
  const float* ef    = (const float*)d_in[1];
  const float* Wn    = (const float*)d_in[2];
  const float* bn    = (const float*)d_in[3];
  const float* Wg    = (const float*)d_in[4];
  const float* bg    = (const float*)d_in[5];
  const float* Wf    = (const float*)d_in[6];
  const float* bf    = (const float*)d_in[7];
  const float* gamma = (const float*)d_in[8];
  const float* beta  = (const float*)d_in[9];
  const float* mean  = (const float*)d_in[10];
  const float* var   = (const float*)d_in[11];
  const int*   eidx  = (const int*)d_in[12];
  float* out = (float*)d_out;

  char* ws = (char*)d_ws;
  float*    nh    = (float*)(ws + 0);                 // 25,600,000 B
  float*    sums  = (float*)(ws + 25600000);          // 25,600,000 B
  unsigned* cnt   = (unsigned*)(ws + 51200000);       //    200,000 B
  _Float16* wt    = (_Float16*)(ws + 51400000);       // 3 x 32,768 B (WnT, WgT, WfT)

  // zero sums + counts (contiguous)
  hipMemsetAsync(sums, 0, 25600000 + 200000, stream);

  prepw_kernel<<<3, 256, 0, stream>>>(Wn, Wg, Wf, wt);
  hist_kernel<<<NE / 256, 256, 0, stream>>>(eidx, cnt);
  node_kernel<<<(NN + 255) / 256, 512, 0, stream>>>(nf, wt, bn, nh);
  edge_kernel<<<256, 512, 0, stream>>>(ef, eidx, wt + 16384, wt + 32768, bg, bf, nh, sums);
  finalize_kernel<<<NN * 32 / 256, 256, 0, stream>>>(nh, sums, cnt, gamma, beta, mean, var, out);
}